// Round 1
// baseline (696.001 us; speedup 1.0000x reference)
//
#include <hip/hip_runtime.h>

#define Bdim 2
#define Hdim 8
#define Sdim 2048
#define Ddim 64
#define PSTR 2056   // P row stride in shorts: +8 pad breaks 16-way bank aliasing
#define NW 8        // waves per block (512 threads)

typedef short bf16x8 __attribute__((ext_vector_type(8)));
typedef short bf16x4 __attribute__((ext_vector_type(4)));
typedef float f32x4 __attribute__((ext_vector_type(4)));

// float -> bf16 bits, round-to-nearest-even
static __device__ __forceinline__ short f2bf(float x) {
  unsigned u = __builtin_bit_cast(unsigned, x);
  unsigned r = (u + 0x7fffu + ((u >> 16) & 1u)) >> 16;
  return (short)r;
}
static __device__ __forceinline__ float bf2f(short x) {
  unsigned u = ((unsigned)(unsigned short)x) << 16;
  return __builtin_bit_cast(float, u);
}
static __device__ __forceinline__ bf16x8 pack8(float4 a, float4 b, float s) {
  bf16x8 r;
  r[0] = f2bf(a.x * s); r[1] = f2bf(a.y * s);
  r[2] = f2bf(a.z * s); r[3] = f2bf(a.w * s);
  r[4] = f2bf(b.x * s); r[5] = f2bf(b.y * s);
  r[6] = f2bf(b.z * s); r[7] = f2bf(b.w * s);
  return r;
}

// One block = (b, h, 16-row q-tile). 8 waves; wave w owns t-cols [w*256, w*256+256).
// 512 threads -> 2 blocks/CU = 16 waves/CU = 4 waves/SIMD (vs 2 at 256 threads):
// the main loop is latency-bound, occupancy is the lever.
// Single sweep: QK MFMA -> p = exp(blend) -> P(bf16) to LDS -> unnormalized PV MFMA.
// Then: cross-wave row-sum reduce; normalize+write attn from LDS; reduce+scale O.
__global__ __launch_bounds__(512, 4) void fused_attn(
    const float* __restrict__ qp, const float* __restrict__ kp,
    const float* __restrict__ vp, const float* __restrict__ covp,
    const float* __restrict__ lamp, const int* __restrict__ maskp,
    float* __restrict__ outO, float* __restrict__ outA)
{
  __shared__ __align__(16) short Pl[16][PSTR];  // 65792 B -> 2 blocks/CU
  __shared__ float Ls[NW][16];
  __shared__ float Lrow[16];

  const int tid  = threadIdx.x;
  const int wv   = tid >> 6;
  const int lane = tid & 63;
  const int quad = lane >> 4;
  const int l15  = lane & 15;

  // h in low bits: the 8 heads sharing a cov/mask tile are consecutive bids
  // (concurrent), so cov/mask stay L3-resident across their 8 uses.
  const int bid = blockIdx.x;
  const int h  = bid & 7;
  const int qt = (bid >> 3) & 127;
  const int b  = bid >> 10;

  const float lam   = lamp[h];
  const float w_qk  = 1.0f / (lam + 1.0f);
  const float w_cov = lam / (lam + 1.0f);
  const float qscale = w_qk * 0.125f;   // fold 1/TEMPERATURE and w_qk into Q

  const int q0 = qt * 16;
  const int bh = b * Hdim + h;

  const float* qbase = qp + ((size_t)bh * Sdim + q0) * Ddim;
  const float* kbase = kp + (size_t)bh * Sdim * Ddim;
  const float* vbase = vp + (size_t)bh * Sdim * Ddim;
  const float* covb  = covp + ((size_t)b * Sdim + q0) * Sdim;
  const int*   mb    = maskp + ((size_t)b * Sdim + q0) * Sdim;
  float* oA = outA + ((size_t)bh * Sdim + q0) * (size_t)Sdim;
  float* oO = outO + ((size_t)bh * Sdim + q0) * Ddim;

  // Q A-frag (16 rows x 64 k), pre-scaled: A[m=l15][k=quad*8+j]
  bf16x8 aq0, aq1;
  {
    const float* qr = qbase + l15 * Ddim + quad * 8;
    float4 x0 = *(const float4*)(qr);
    float4 x1 = *(const float4*)(qr + 4);
    aq0 = pack8(x0, x1, qscale);
    float4 y0 = *(const float4*)(qr + 32);
    float4 y1 = *(const float4*)(qr + 36);
    aq1 = pack8(y0, y1, qscale);
  }

  const int tbeg = wv * (Sdim / NW);
  const int tend = tbeg + (Sdim / NW);

  float lsum[4] = {0.f, 0.f, 0.f, 0.f};
  f32x4 oacc[4];
#pragma unroll
  for (int n = 0; n < 4; ++n) oacc[n] = (f32x4){0.f, 0.f, 0.f, 0.f};

#pragma unroll 2
  for (int t0 = tbeg; t0 < tend; t0 += 32) {
    // ---- QK^T for 32 t-cols ----
    f32x4 acc[2];
#pragma unroll
    for (int n = 0; n < 2; ++n) {
      const float* kr = kbase + (size_t)(t0 + n * 16 + l15) * Ddim + quad * 8;
      float4 x0 = *(const float4*)(kr);
      float4 x1 = *(const float4*)(kr + 4);
      float4 y0 = *(const float4*)(kr + 32);
      float4 y1 = *(const float4*)(kr + 36);
      bf16x8 b0 = pack8(x0, x1, 1.0f);
      bf16x8 b1 = pack8(y0, y1, 1.0f);
      f32x4 a = {0.f, 0.f, 0.f, 0.f};
      a = __builtin_amdgcn_mfma_f32_16x16x32_bf16(aq0, b0, a, 0, 0, 0);
      a = __builtin_amdgcn_mfma_f32_16x16x32_bf16(aq1, b1, a, 0, 0, 0);
      acc[n] = a;
    }

    // ---- V B-frags direct from global: B[k=t][n=d], lane: n=l15, k=quad*8+j ----
    bf16x8 bv[4];
#pragma unroll
    for (int nb = 0; nb < 4; ++nb) {
      const float* vcol = vbase + (size_t)(t0 + quad * 8) * Ddim + nb * 16 + l15;
#pragma unroll
      for (int j = 0; j < 8; ++j) bv[nb][j] = f2bf(vcol[j * Ddim]);
    }

    // ---- blend + mask + exp; stash unnormalized p ----
#pragma unroll
    for (int n = 0; n < 2; ++n) {
      const int col = t0 + n * 16 + l15;
#pragma unroll
      for (int r = 0; r < 4; ++r) {
        const int row = quad * 4 + r;           // C/D layout row
        float c = covb[row * Sdim + col];
        int   m = mb[row * Sdim + col];
        float logit = acc[n][r] + w_cov * c;
        float p = m ? __expf(logit) : 0.0f;     // |logit| small: no max-sub needed
        lsum[r] += p;
        Pl[row][col] = f2bf(p);
      }
    }

    // ---- PV accumulate (unnormalized): A-frag via LDS round-trip ----
    bf16x8 pa = *(const bf16x8*)&Pl[l15][t0 + quad * 8];
#pragma unroll
    for (int nb = 0; nb < 4; ++nb)
      oacc[nb] = __builtin_amdgcn_mfma_f32_16x16x32_bf16(pa, bv[nb], oacc[nb], 0, 0, 0);
  }

  // ---- cross-wave row-sum reduction ----
#pragma unroll
  for (int r = 0; r < 4; ++r) {
    float s = lsum[r];
    s += __shfl_xor(s, 1, 16);
    s += __shfl_xor(s, 2, 16);
    s += __shfl_xor(s, 4, 16);
    s += __shfl_xor(s, 8, 16);
    if (l15 == 0) Ls[wv][quad * 4 + r] = s;
  }
  __syncthreads();
  if (tid < 16) {
    float s = 0.f;
#pragma unroll
    for (int w2 = 0; w2 < NW; ++w2) s += Ls[w2][tid];
    Lrow[tid] = 1.0f / s;
  }
  __syncthreads();

  // ---- normalize + write attn (each wave: its own 256-col slice, all 16 rows) ----
#pragma unroll 1
  for (int row = 0; row < 16; ++row) {
    const float rinv = Lrow[row];
    float* orow = oA + (size_t)row * Sdim;
    const int c0 = tbeg + lane * 4;
    bf16x4 pv = *(const bf16x4*)&Pl[row][c0];
    f32x4 o;
    o[0] = bf2f(pv[0]) * rinv;
    o[1] = bf2f(pv[1]) * rinv;
    o[2] = bf2f(pv[2]) * rinv;
    o[3] = bf2f(pv[3]) * rinv;
    __builtin_nontemporal_store(o, (f32x4*)&orow[c0]);
  }
  __syncthreads();   // all P reads done; safe to alias

  // ---- O reduction across waves (alias P region), scale by 1/l, store ----
  float* Ored = (float*)&Pl[0][0];   // [NW][64][16] f32 = 32 KB, fits in P alias
#pragma unroll
  for (int nb = 0; nb < 4; ++nb)
#pragma unroll
    for (int r = 0; r < 4; ++r)
      Ored[((wv * 64 + lane) * 16) + nb * 4 + r] = oacc[nb][r];
  __syncthreads();
  if (wv < 4) {
#pragma unroll
    for (int r = 0; r < 4; ++r) {
      float s = 0.f;
#pragma unroll
      for (int w2 = 0; w2 < NW; ++w2)
        s += Ored[((w2 * 64 + lane) * 16) + wv * 4 + r];
      const int row = quad * 4 + r;
      __builtin_nontemporal_store(s * Lrow[row], &oO[row * Ddim + wv * 16 + l15]);
    }
  }
}

extern "C" void kernel_launch(void* const* d_in, const int* in_sizes, int n_in,
                              void* d_out, int out_size, void* d_ws, size_t ws_size,
                              hipStream_t stream) {
  const float* q    = (const float*)d_in[0];
  const float* k    = (const float*)d_in[1];
  const float* v    = (const float*)d_in[2];
  const float* cov  = (const float*)d_in[3];
  const float* lam  = (const float*)d_in[4];
  const int*   mask = (const int*)d_in[5];
  float* outO = (float*)d_out;
  float* outA = outO + (size_t)Bdim * Hdim * Sdim * Ddim;
  (void)d_ws; (void)ws_size;

  dim3 grid(Bdim * Hdim * (Sdim / 16));   // 2048 blocks x 512 threads
  fused_attn<<<grid, 512, 0, stream>>>(q, k, v, cov, lam, mask, outO, outA);
}

// Round 2
// 633.352 us; speedup vs baseline: 1.0989x; 1.0989x over previous
//
#include <hip/hip_runtime.h>

#define Bdim 2
#define Hdim 8
#define Sdim 2048
#define Ddim 64
#define PSTR 2056   // P row stride in shorts: +8 pad breaks 16-way bank aliasing
#define NW 8        // waves per block (512 threads)

typedef short bf16x8 __attribute__((ext_vector_type(8)));
typedef short bf16x4 __attribute__((ext_vector_type(4)));
typedef float f32x4 __attribute__((ext_vector_type(4)));

// float -> bf16 bits via hardware cvt (RNE, same rounding as manual path,
// but 1 op per pair via v_cvt_pk_bf16_f32 instead of ~4 VALU ops/elem)
static __device__ __forceinline__ short f2bf(float x) {
  return __builtin_bit_cast(short, (__bf16)x);
}
static __device__ __forceinline__ float bf2f(short x) {
  unsigned u = ((unsigned)(unsigned short)x) << 16;
  return __builtin_bit_cast(float, u);
}
static __device__ __forceinline__ bf16x8 pack8(float4 a, float4 b, float s) {
  bf16x8 r;
  r[0] = f2bf(a.x * s); r[1] = f2bf(a.y * s);
  r[2] = f2bf(a.z * s); r[3] = f2bf(a.w * s);
  r[4] = f2bf(b.x * s); r[5] = f2bf(b.y * s);
  r[6] = f2bf(b.z * s); r[7] = f2bf(b.w * s);
  return r;
}
static __device__ __forceinline__ bf16x8 pack8n(float4 a, float4 b) {
  bf16x8 r;
  r[0] = f2bf(a.x); r[1] = f2bf(a.y); r[2] = f2bf(a.z); r[3] = f2bf(a.w);
  r[4] = f2bf(b.x); r[5] = f2bf(b.y); r[6] = f2bf(b.z); r[7] = f2bf(b.w);
  return r;
}

// Issue 8 vec loads of K rows [TROW, TROW+32) for this lane's B-frag.
#define LOADK(KD, TROW)                                                        \
  {                                                                            \
    const float* kr0 = kbase + (size_t)((TROW) + l15) * Ddim + quad * 8;       \
    KD[0] = *(const float4*)(kr0);                                             \
    KD[1] = *(const float4*)(kr0 + 4);                                         \
    KD[2] = *(const float4*)(kr0 + 32);                                        \
    KD[3] = *(const float4*)(kr0 + 36);                                        \
    const float* kr1 = kr0 + 16 * Ddim;                                        \
    KD[4] = *(const float4*)(kr1);                                             \
    KD[5] = *(const float4*)(kr1 + 4);                                         \
    KD[6] = *(const float4*)(kr1 + 32);                                        \
    KD[7] = *(const float4*)(kr1 + 36);                                        \
  }

// One 32-col tile. Issue order == consumption order (vmcnt is FIFO):
//  cov/mask (blend) and V (PV) issue at top, covered by QK MFMA phase;
//  K for the NEXT tile issues right after QK, covered by blend+exp+PV.
// The compiler then emits counted vmcnt waits: QK waits only the K regs
// (prefetched last body), blend waits cov/mask, PV waits V — no full drains.
#define QK_BODY(KCUR, KNEXT, T0, TNEXT)                                        \
  {                                                                            \
    float cvf[2][4]; int mki[2][4];                                            \
    _Pragma("unroll") for (int n = 0; n < 2; ++n)                              \
      _Pragma("unroll") for (int r = 0; r < 4; ++r) {                          \
        const int col = (T0) + n * 16 + l15;                                   \
        cvf[n][r] = covb[(quad * 4 + r) * Sdim + col];                         \
        mki[n][r] = mb[(quad * 4 + r) * Sdim + col];                           \
      }                                                                        \
    float vfl[4][8];                                                           \
    _Pragma("unroll") for (int nb = 0; nb < 4; ++nb) {                         \
      const float* vcol = vbase + (size_t)((T0) + quad * 8) * Ddim + nb * 16 + l15; \
      _Pragma("unroll") for (int j = 0; j < 8; ++j) vfl[nb][j] = vcol[j * Ddim]; \
    }                                                                          \
    f32x4 acc[2];                                                              \
    _Pragma("unroll") for (int n = 0; n < 2; ++n) {                            \
      bf16x8 b0 = pack8n(KCUR[n * 4 + 0], KCUR[n * 4 + 1]);                    \
      bf16x8 b1 = pack8n(KCUR[n * 4 + 2], KCUR[n * 4 + 3]);                    \
      f32x4 a = {0.f, 0.f, 0.f, 0.f};                                          \
      a = __builtin_amdgcn_mfma_f32_16x16x32_bf16(aq0, b0, a, 0, 0, 0);        \
      a = __builtin_amdgcn_mfma_f32_16x16x32_bf16(aq1, b1, a, 0, 0, 0);        \
      acc[n] = a;                                                              \
    }                                                                          \
    LOADK(KNEXT, TNEXT);                                                       \
    _Pragma("unroll") for (int n = 0; n < 2; ++n) {                            \
      const int col = (T0) + n * 16 + l15;                                     \
      _Pragma("unroll") for (int r = 0; r < 4; ++r) {                          \
        const int row = quad * 4 + r;                                          \
        float logit = acc[n][r] + w_cov * cvf[n][r];                           \
        float p = mki[n][r] ? __expf(logit) : 0.0f;                            \
        lsum[r] += p;                                                          \
        Pl[row][col] = f2bf(p);                                                \
      }                                                                        \
    }                                                                          \
    bf16x8 pa = *(const bf16x8*)&Pl[l15][(T0) + quad * 8];                     \
    _Pragma("unroll") for (int nb = 0; nb < 4; ++nb) {                         \
      bf16x8 bvv;                                                              \
      _Pragma("unroll") for (int j = 0; j < 8; ++j) bvv[j] = f2bf(vfl[nb][j]); \
      oacc[nb] = __builtin_amdgcn_mfma_f32_16x16x32_bf16(pa, bvv, oacc[nb], 0, 0, 0); \
    }                                                                          \
  }

// One block = (b, h, 16-row q-tile). 8 waves; wave w owns t-cols [w*256, w*256+256).
// Software-pipelined main loop: see QK_BODY. 2 blocks/CU (LDS-capped).
__global__ __launch_bounds__(512, 4) void fused_attn(
    const float* __restrict__ qp, const float* __restrict__ kp,
    const float* __restrict__ vp, const float* __restrict__ covp,
    const float* __restrict__ lamp, const int* __restrict__ maskp,
    float* __restrict__ outO, float* __restrict__ outA)
{
  __shared__ __align__(16) short Pl[16][PSTR];  // 65792 B -> 2 blocks/CU
  __shared__ float Ls[NW][16];
  __shared__ float Lrow[16];

  const int tid  = threadIdx.x;
  const int wv   = tid >> 6;
  const int lane = tid & 63;
  const int quad = lane >> 4;
  const int l15  = lane & 15;

  // h in low bits: the 8 heads sharing a cov/mask tile are consecutive bids
  // (concurrent), so cov/mask stay L3-resident across their 8 uses.
  const int bid = blockIdx.x;
  const int h  = bid & 7;
  const int qt = (bid >> 3) & 127;
  const int b  = bid >> 10;

  const float lam   = lamp[h];
  const float w_qk  = 1.0f / (lam + 1.0f);
  const float w_cov = lam / (lam + 1.0f);
  const float qscale = w_qk * 0.125f;   // fold 1/TEMPERATURE and w_qk into Q

  const int q0 = qt * 16;
  const int bh = b * Hdim + h;

  const float* qbase = qp + ((size_t)bh * Sdim + q0) * Ddim;
  const float* kbase = kp + (size_t)bh * Sdim * Ddim;
  const float* vbase = vp + (size_t)bh * Sdim * Ddim;
  const float* covb  = covp + ((size_t)b * Sdim + q0) * Sdim;
  const int*   mb    = maskp + ((size_t)b * Sdim + q0) * Sdim;
  float* oA = outA + ((size_t)bh * Sdim + q0) * (size_t)Sdim;
  float* oO = outO + ((size_t)bh * Sdim + q0) * Ddim;

  // Q A-frag (16 rows x 64 k), pre-scaled: A[m=l15][k=quad*8+j]
  bf16x8 aq0, aq1;
  {
    const float* qr = qbase + l15 * Ddim + quad * 8;
    float4 x0 = *(const float4*)(qr);
    float4 x1 = *(const float4*)(qr + 4);
    aq0 = pack8(x0, x1, qscale);
    float4 y0 = *(const float4*)(qr + 32);
    float4 y1 = *(const float4*)(qr + 36);
    aq1 = pack8(y0, y1, qscale);
  }

  const int tbeg = wv * (Sdim / NW);
  const int tend = tbeg + (Sdim / NW);

  float lsum[4] = {0.f, 0.f, 0.f, 0.f};
  f32x4 oacc[4];
#pragma unroll
  for (int n = 0; n < 4; ++n) oacc[n] = (f32x4){0.f, 0.f, 0.f, 0.f};

  // Manual 2x unrolled A/B K-register double-buffer (no runtime-indexed
  // arrays; tend-tbeg = 256 -> 8 bodies -> 4 clean pairs).
  float4 kA[8], kB[8];
  LOADK(kA, tbeg);
  for (int t0 = tbeg; t0 < tend; t0 += 64) {
    QK_BODY(kA, kB, t0, t0 + 32);
    const int tnx = (t0 + 64 < tend) ? (t0 + 64) : tbeg;  // last prefetch: dummy
    QK_BODY(kB, kA, t0 + 32, tnx);
  }

  // ---- cross-wave row-sum reduction ----
#pragma unroll
  for (int r = 0; r < 4; ++r) {
    float s = lsum[r];
    s += __shfl_xor(s, 1, 16);
    s += __shfl_xor(s, 2, 16);
    s += __shfl_xor(s, 4, 16);
    s += __shfl_xor(s, 8, 16);
    if (l15 == 0) Ls[wv][quad * 4 + r] = s;
  }
  __syncthreads();
  if (tid < 16) {
    float s = 0.f;
#pragma unroll
    for (int w2 = 0; w2 < NW; ++w2) s += Ls[w2][tid];
    Lrow[tid] = 1.0f / s;
  }
  __syncthreads();

  // ---- normalize + write attn (each wave: its own 256-col slice, all 16 rows) ----
#pragma unroll 1
  for (int row = 0; row < 16; ++row) {
    const float rinv = Lrow[row];
    float* orow = oA + (size_t)row * Sdim;
    const int c0 = tbeg + lane * 4;
    bf16x4 pv = *(const bf16x4*)&Pl[row][c0];
    f32x4 o;
    o[0] = bf2f(pv[0]) * rinv;
    o[1] = bf2f(pv[1]) * rinv;
    o[2] = bf2f(pv[2]) * rinv;
    o[3] = bf2f(pv[3]) * rinv;
    __builtin_nontemporal_store(o, (f32x4*)&orow[c0]);
  }
  __syncthreads();   // all P reads done; safe to alias

  // ---- O reduction across waves (alias P region), scale by 1/l, store ----
  float* Ored = (float*)&Pl[0][0];   // [NW][64][16] f32 = 32 KB, fits in P alias
#pragma unroll
  for (int nb = 0; nb < 4; ++nb)
#pragma unroll
    for (int r = 0; r < 4; ++r)
      Ored[((wv * 64 + lane) * 16) + nb * 4 + r] = oacc[nb][r];
  __syncthreads();
  if (wv < 4) {
#pragma unroll
    for (int r = 0; r < 4; ++r) {
      float s = 0.f;
#pragma unroll
      for (int w2 = 0; w2 < NW; ++w2)
        s += Ored[((w2 * 64 + lane) * 16) + wv * 4 + r];
      const int row = quad * 4 + r;
      __builtin_nontemporal_store(s * Lrow[row], &oO[row * Ddim + wv * 16 + l15]);
    }
  }
}

extern "C" void kernel_launch(void* const* d_in, const int* in_sizes, int n_in,
                              void* d_out, int out_size, void* d_ws, size_t ws_size,
                              hipStream_t stream) {
  const float* q    = (const float*)d_in[0];
  const float* k    = (const float*)d_in[1];
  const float* v    = (const float*)d_in[2];
  const float* cov  = (const float*)d_in[3];
  const float* lam  = (const float*)d_in[4];
  const int*   mask = (const int*)d_in[5];
  float* outO = (float*)d_out;
  float* outA = outO + (size_t)Bdim * Hdim * Sdim * Ddim;
  (void)d_ws; (void)ws_size;

  dim3 grid(Bdim * Hdim * (Sdim / 16));   // 2048 blocks x 512 threads
  fused_attn<<<grid, 512, 0, stream>>>(q, k, v, cov, lam, mask, outO, outA);
}